// Round 5
// baseline (3989.684 us; speedup 1.0000x reference)
//
#include <hip/hip_runtime.h>
#include <hip/hip_bf16.h>

// Problem constants (match reference setup_inputs)
#define Bb 64
#define Tt 256
#define Ee 300
#define Hh 512
#define NSTEP (2 * Tt - 1)  // 511
#define NNODE (Tt - 1)      // 255 internal nodes max per batch
#define N5H (5 * Hh)        // 2560

typedef __bf16 v8bf __attribute__((ext_vector_type(8)));
typedef float v4f __attribute__((ext_vector_type(4)));
typedef unsigned long long u64;
typedef unsigned int u32;
typedef unsigned char u8;

__device__ __forceinline__ float sigm(float x) { return 1.f / (1.f + __expf(-x)); }

// ---------------------------------------------------------------------------
// Phase 1: leaf buffer projections.
// ---------------------------------------------------------------------------
__global__ __launch_bounds__(256) void leaf_kernel(
    const float* __restrict__ x, const float* __restrict__ Wx,
    const float* __restrict__ bx, const float* __restrict__ Wg,
    const float* __restrict__ bg,
    __hip_bfloat16* __restrict__ leaf_h, float* __restrict__ leaf_c)
{
    __shared__ __align__(16) float xs[16][304];
    const int tid = threadIdx.x;
    const int n = blockIdx.x * 256 + tid;
    const long r0 = (long)blockIdx.y * 16;

    for (int i = tid; i < 16 * Ee; i += 256) {
        int r = i / Ee, k = i - r * Ee;
        xs[r][k] = x[(r0 + r) * Ee + k];
    }
    __syncthreads();

    float accx[16], accg[16];
    const float bxv = bx[n], bgv = bg[n];
#pragma unroll
    for (int r = 0; r < 16; r++) { accx[r] = bxv; accg[r] = bgv; }

    for (int k = 0; k < Ee; k += 4) {
        float wx[4], wg[4];
#pragma unroll
        for (int u = 0; u < 4; u++) {
            wx[u] = Wx[(long)(k + u) * Hh + n];
            wg[u] = Wg[(long)(k + u) * Hh + n];
        }
#pragma unroll
        for (int r = 0; r < 16; r++) {
            const float4 xv = *(const float4*)&xs[r][k];
            accx[r] = fmaf(xv.x, wx[0], accx[r]);
            accx[r] = fmaf(xv.y, wx[1], accx[r]);
            accx[r] = fmaf(xv.z, wx[2], accx[r]);
            accx[r] = fmaf(xv.w, wx[3], accx[r]);
            accg[r] = fmaf(xv.x, wg[0], accg[r]);
            accg[r] = fmaf(xv.y, wg[1], accg[r]);
            accg[r] = fmaf(xv.z, wg[2], accg[r]);
            accg[r] = fmaf(xv.w, wg[3], accg[r]);
        }
    }
#pragma unroll
    for (int r = 0; r < 16; r++) {
        const float c = accx[r];
        const float h = sigm(accg[r]) * tanhf(c);
        const long idx = (r0 + r) * Hh + n;
        leaf_c[idx] = c;
        leaf_h[idx] = __float2bfloat16(h);
    }
}

// ---------------------------------------------------------------------------
// Phase 2: schedule (zeroes the 64-dword / 256-byte barrier slot array).
// ---------------------------------------------------------------------------
__global__ __launch_bounds__(64) void sched_kernel(
    const int* __restrict__ trans,
    int* __restrict__ node_l, int* __restrict__ node_r,
    int* __restrict__ root_src, int* __restrict__ offs,
    int* __restrict__ items, int* __restrict__ max_lv,
    int* __restrict__ slots)
{
    __shared__ short stck[Bb][Tt];
    __shared__ unsigned char lvl[Bb][NNODE];
    __shared__ unsigned char trans_s[NSTEP][Bb];
    __shared__ int counts[256];
    __shared__ int offs_s[257];
    __shared__ int maxl_s;
    const int b = threadIdx.x;

    if (b == 0) maxl_s = 0;
    slots[b] = 0;  // 64 dwords = 256 byte-slots
    for (int i = b; i < 256; i += Bb) counts[i] = 0;
    for (int i4 = b; i4 < (NSTEP * Bb) / 4; i4 += Bb) {
        const int4 v = ((const int4*)trans)[i4];
        const int f = 4 * i4;
        trans_s[(f + 0) >> 6][(f + 0) & 63] = (unsigned char)v.x;
        trans_s[(f + 1) >> 6][(f + 1) & 63] = (unsigned char)v.y;
        trans_s[(f + 2) >> 6][(f + 2) & 63] = (unsigned char)v.z;
        trans_s[(f + 3) >> 6][(f + 3) & 63] = (unsigned char)v.w;
    }
    __syncthreads();

    int sp = 0, bp = Tt, nid = 0, maxl = 0;
    for (int t = 0; t < NSTEP; t++) {
        if (trans_s[t][b] == 0) {
            bp -= 1;
            stck[b][sp] = (short)bp; sp += 1;
        } else {
            const int rs = stck[b][sp - 1];
            const int ls = stck[b][sp - 2];
            const int l_lv = (ls < Tt) ? 0 : (int)lvl[b][ls - Tt];
            const int r_lv = (rs < Tt) ? 0 : (int)lvl[b][rs - Tt];
            const int le = 1 + (l_lv > r_lv ? l_lv : r_lv);
            lvl[b][nid] = (unsigned char)le;
            node_l[b * NNODE + nid] = ls;
            node_r[b * NNODE + nid] = rs;
            if (le > maxl) maxl = le;
            sp -= 2;
            stck[b][sp] = (short)(Tt + nid); sp += 1;
            nid += 1;
        }
    }
    root_src[b] = (int)stck[b][0];
    for (int i = 0; i < nid; i++) atomicAdd(&counts[lvl[b][i]], 1);
    atomicMax(&maxl_s, maxl);
    __syncthreads();
    if (b == 0) {
        int acc = 0;
        for (int l = 0; l < 256; l++) { offs_s[l] = acc; acc += counts[l]; }
        offs_s[256] = acc;
        max_lv[0] = maxl_s;
    }
    __syncthreads();
    for (int i = b; i < 256; i += Bb) counts[i] = offs_s[i];
    __syncthreads();
    for (int i = 0; i < nid; i++) {
        const int pos = atomicAdd(&counts[lvl[b][i]], 1);
        items[pos] = (b << 16) | i;
    }
    for (int i = b; i < 257; i += Bb) offs[i] = offs_s[i];
}

// ---------------------------------------------------------------------------
// Phase 3: level-synchronous tree evaluation.
// R5: (1) byte barrier slots — poll = 1 dword load/lane (4x less LLC poll
// traffic); (2) prep on wave 1, overlapping wave 0's poll; (3) child-h A
// gather via coalesced LDS staging (one wave-instruction per 1 KB half-row)
// in 2 sub-chunks of 32 items; (4) epilogue 1 gate-set/lane + shfl pack.
// Data coherence unchanged from R4 (proven): node h/c sc1-stored (LLC),
// gathered with cached loads (line written once, read only after its level;
// dispatch-start acquire invalidates stale L1/L2).
// ---------------------------------------------------------------------------
__global__ __launch_bounds__(512) void tree_kernel(
    const float* __restrict__ Wr, const float* __restrict__ br,
    const __hip_bfloat16* __restrict__ leaf_h, const float* __restrict__ leaf_c,
    __hip_bfloat16* __restrict__ node_h, float* __restrict__ node_c,
    const int* __restrict__ node_l, const int* __restrict__ node_r,
    const int* __restrict__ root_src, const int* __restrict__ offs,
    const int* __restrict__ items, const int* __restrict__ max_level,
    float* __restrict__ out, int* __restrict__ slots)
{
    __shared__ __align__(16) __bf16 Wt[16][1032];   // W slice [local col][k]
    __shared__ __align__(16) __bf16 stage[64][520]; // 64 child half-rows (1KB+pad)
    __shared__ float Csp[4][32][17];                // per-kq partials, sub-chunk
    __shared__ float brs[16];
    __shared__ const __hip_bfloat16* hP[128];       // [m]=left, [64+m]=right
    __shared__ const float* cPl[64];
    __shared__ const float* cPr[64];
    __shared__ int outm[64];

    const int tid = threadIdx.x;
    const int g = blockIdx.x;  // column group: j = 2g, 2g+1

    // Load W_r slice as bf16, transposed. Local col c: jj=c/5, gate=c%5.
    for (int idx = tid; idx < 16 * 1024; idx += 512) {
        const int c = idx >> 10;
        const int k = idx & 1023;
        float v = 0.f;
        if (c < 10) {
            const int col = (c % 5) * Hh + 2 * g + (c / 5);
            v = Wr[(long)k * N5H + col];
        }
        Wt[c][k] = (__bf16)v;
    }
    if (tid < 16) {
        float v = 0.f;
        if (tid < 10) v = br[(tid % 5) * Hh + 2 * g + (tid / 5)];
        brs[tid] = v;
    }
    __syncthreads();

    const int ML = max_level[0];
    const int wave = tid >> 6;
    const int lane = tid & 63;
    const int quad = lane >> 4;
    const int l15 = lane & 15;
    const int mt = wave & 1;   // M-tile within 32-row sub-chunk
    const int kq = wave >> 1;  // K quarter of 1024 (0,1: left child; 2,3: right)

    u32* node_h32 = (u32*)node_h;  // 2 bf16 per u32

    // prep on WAVE 1 — overlaps wave 0's barrier poll.
    auto prep = [&](int base, int M) {
        if (wave == 1) {
            const int m = lane;
            const int it = items[base + (m < M ? m : 0)];
            const int b = it >> 16;
            const int nd = it & 0xffff;
            const int ls = node_l[b * NNODE + nd];
            const int rs = node_r[b * NNODE + nd];
            if (ls < Tt) {
                hP[m]  = leaf_h + ((long)b * Tt + ls) * Hh;
                cPl[m] = leaf_c + ((long)b * Tt + ls) * Hh;
            } else {
                hP[m]  = node_h + ((long)b * NNODE + (ls - Tt)) * Hh;
                cPl[m] = node_c + ((long)b * NNODE + (ls - Tt)) * Hh;
            }
            if (rs < Tt) {
                hP[64 + m] = leaf_h + ((long)b * Tt + rs) * Hh;
                cPr[m]     = leaf_c + ((long)b * Tt + rs) * Hh;
            } else {
                hP[64 + m] = node_h + ((long)b * NNODE + (rs - Tt)) * Hh;
                cPr[m]     = node_c + ((long)b * NNODE + (rs - Tt)) * Hh;
            }
            int fl = it;
            if (Tt + nd == root_src[b]) fl |= (1 << 30);  // root marker
            if (m >= M) fl |= (1 << 29);                  // pad marker
            outm[m] = fl;
        }
    };

    for (int lev = 1; lev <= ML; lev++) {
        const int s = offs[lev], e = offs[lev + 1];
        prep(s, (e - s < 64) ? (e - s) : 64);   // wave 1
        if (lev > 1 && wave == 0) {             // wave 0: poll byte slots
            const u32 need = (u32)(lev - 1);
            const u32* sl = (const u32*)slots + lane;
            for (;;) {
                const u32 v = __hip_atomic_load(sl, __ATOMIC_RELAXED, __HIP_MEMORY_SCOPE_AGENT);
                const bool ok = ((v & 0xffu) >= need) & (((v >> 8) & 0xffu) >= need)
                              & (((v >> 16) & 0xffu) >= need) & ((v >> 24) >= need);
                if (__all(ok)) break;
            }
        }
        __syncthreads();

        for (int base = s; base < e; base += 64) {
            const int M = (e - base < 64) ? (e - base) : 64;
            if (base != s) { prep(base, M); __syncthreads(); }
            const int nsc = (M > 32) ? 2 : 1;

            for (int sc = 0; sc < nsc; sc++) {
                // Child-c prefetch for this sub-chunk (wave 0; consumed in
                // its own epilogue — same lane mapping).
                float clv = 0.f, crv = 0.f;
                if (wave == 0) {
                    const int m = sc * 32 + (lane >> 1);
                    const int j = 2 * g + (lane & 1);
                    clv = cPl[m][j];
                    crv = cPr[m][j];
                }
                // Stage 64 child half-rows, coalesced: one wave-instruction
                // per 1 KB row (64 lanes x 16 B).
#pragma unroll
                for (int i = 0; i < 8; i++) {
                    const int row = wave * 8 + i;
                    const int m = sc * 32 + (row & 31);
                    const __hip_bfloat16* rp = (row < 32) ? hP[m] : hP[64 + m];
                    const v8bf v = *(const v8bf*)(rp + lane * 8);
                    *(v8bf*)&stage[row][lane * 8] = v;
                }
                __syncthreads();

                // MFMA: wave (mt, kq): 16-row tile mt, K-quarter kq.
                v4f acc = {0.f, 0.f, 0.f, 0.f};
#pragma unroll
                for (int t = 0; t < 8; t++) {
                    const int kloc = (kq & 1) * 256 + t * 32 + quad * 8;
                    const int srow = ((kq & 2) ? 32 : 0) + mt * 16 + l15;
                    const v8bf a = *(const v8bf*)&stage[srow][kloc];
                    const v8bf w = *(const v8bf*)&Wt[l15][((kq & 2) ? 512 : 0) + kloc];
                    acc = __builtin_amdgcn_mfma_f32_16x16x32_bf16(a, w, acc, 0, 0, 0);
                }
#pragma unroll
                for (int rg = 0; rg < 4; rg++)
                    Csp[kq][mt * 16 + quad * 4 + rg][l15] = acc[rg];
                __syncthreads();

                // Epilogue: wave 0, one (item, j-column) per lane.
                if (wave == 0) {
                    const int ml = lane >> 1;       // item within sub-chunk
                    const int jj = lane & 1;
                    const int m = sc * 32 + ml;
                    const int info = outm[m];
                    float gate[5];
#pragma unroll
                    for (int gi = 0; gi < 5; gi++)
                        gate[gi] = Csp[0][ml][jj * 5 + gi] + Csp[1][ml][jj * 5 + gi]
                                 + Csp[2][ml][jj * 5 + gi] + Csp[3][ml][jj * 5 + gi]
                                 + brs[jj * 5 + gi];
                    const float c = sigm(gate[0]) * tanhf(gate[3])
                                  + sigm(gate[1]) * clv + sigm(gate[2]) * crv;
                    const float h = sigm(gate[4]) * tanhf(c);
                    const float ho = __shfl_xor(h, 1);  // partner column
                    if (!(info & (1 << 29))) {
                        const int b = (info >> 16) & 63;
                        const int nd = info & 0xffff;
                        __hip_atomic_store(node_c + ((long)b * NNODE + nd) * Hh + 2 * g + jj, c,
                                           __ATOMIC_RELAXED, __HIP_MEMORY_SCOPE_AGENT);
                        if (jj == 0) {
                            const __hip_bfloat16 h0 = __float2bfloat16(h);
                            const __hip_bfloat16 h1 = __float2bfloat16(ho);
                            const u32 pack = (u32)(*(const unsigned short*)&h0)
                                           | ((u32)(*(const unsigned short*)&h1) << 16);
                            __hip_atomic_store(node_h32 + ((long)b * NNODE + nd) * (Hh / 2) + g, pack,
                                               __ATOMIC_RELAXED, __HIP_MEMORY_SCOPE_AGENT);
                        }
                        if (info & (1 << 30)) out[(long)b * Hh + 2 * g + jj] = h;
                    }
                }
                __syncthreads();  // Csp/stage/outm reuse
            }
        }

        // Arrive: tid0 (wave 0 — the wave that issued ALL sc1 stores) drains
        // its wave's stores to the LLC, then one relaxed byte store.
        if (lev < ML && tid == 0) {
            __builtin_amdgcn_s_waitcnt(0);
            __hip_atomic_store((u8*)slots + blockIdx.x, (u8)lev,
                               __ATOMIC_RELAXED, __HIP_MEMORY_SCOPE_AGENT);
        }
    }
}

// ---------------------------------------------------------------------------
extern "C" void kernel_launch(void* const* d_in, const int* in_sizes, int n_in,
                              void* d_out, int out_size, void* d_ws, size_t ws_size,
                              hipStream_t stream)
{
    const float* x   = (const float*)d_in[0];
    const int* trans = (const int*)d_in[1];
    const float* Wx  = (const float*)d_in[2];
    const float* bx  = (const float*)d_in[3];
    const float* Wg  = (const float*)d_in[4];
    const float* bg  = (const float*)d_in[5];
    const float* Wr  = (const float*)d_in[6];
    const float* br  = (const float*)d_in[7];
    float* out = (float*)d_out;

    char* p = (char*)d_ws;
    auto take = [&](size_t bytes) -> char* {
        char* r = p;
        p += (bytes + 255) & ~(size_t)255;
        return r;
    };
    __hip_bfloat16* leaf_h = (__hip_bfloat16*)take((size_t)Bb * Tt * Hh * 2);
    float* leaf_c          = (float*)take((size_t)Bb * Tt * Hh * 4);
    __hip_bfloat16* node_h = (__hip_bfloat16*)take((size_t)Bb * NNODE * Hh * 2);
    float* node_c          = (float*)take((size_t)Bb * NNODE * Hh * 4);
    int* node_l   = (int*)take((size_t)Bb * NNODE * 4);
    int* node_r   = (int*)take((size_t)Bb * NNODE * 4);
    int* root_src = (int*)take(Bb * 4);
    int* offs     = (int*)take(257 * 4);
    int* items    = (int*)take((size_t)Bb * NNODE * 4);
    int* max_lv   = (int*)take(4);
    int* slots    = (int*)take(64 * 4);   // 256 byte-slots

    hipLaunchKernelGGL(leaf_kernel, dim3(Hh / 256, (Bb * Tt) / 16), dim3(256), 0, stream,
                       x, Wx, bx, Wg, bg, leaf_h, leaf_c);
    hipLaunchKernelGGL(sched_kernel, dim3(1), dim3(64), 0, stream,
                       trans, node_l, node_r, root_src, offs, items, max_lv, slots);

    void* args[] = { (void*)&Wr, (void*)&br, (void*)&leaf_h, (void*)&leaf_c,
                     (void*)&node_h, (void*)&node_c, (void*)&node_l, (void*)&node_r,
                     (void*)&root_src, (void*)&offs, (void*)&items, (void*)&max_lv,
                     (void*)&out, (void*)&slots };
    hipLaunchCooperativeKernel((const void*)tree_kernel, dim3(256), dim3(512),
                               args, 0, stream);
}

// Round 6
// 2362.750 us; speedup vs baseline: 1.6886x; 1.6886x over previous
//
#include <hip/hip_runtime.h>
#include <hip/hip_bf16.h>

// Problem constants (match reference setup_inputs)
#define Bb 64
#define Tt 256
#define Ee 300
#define Hh 512
#define NSTEP (2 * Tt - 1)  // 511
#define NNODE (Tt - 1)      // 255 internal nodes max per batch
#define N5H (5 * Hh)        // 2560

typedef __bf16 v8bf __attribute__((ext_vector_type(8)));
typedef float v4f __attribute__((ext_vector_type(4)));
typedef unsigned long long u64;
typedef unsigned int u32;
typedef unsigned char u8;

__device__ __forceinline__ float sigm(float x) { return 1.f / (1.f + __expf(-x)); }

// ---------------------------------------------------------------------------
// Phase 1: leaf buffer projections.
// ---------------------------------------------------------------------------
__global__ __launch_bounds__(256) void leaf_kernel(
    const float* __restrict__ x, const float* __restrict__ Wx,
    const float* __restrict__ bx, const float* __restrict__ Wg,
    const float* __restrict__ bg,
    __hip_bfloat16* __restrict__ leaf_h, float* __restrict__ leaf_c)
{
    __shared__ __align__(16) float xs[16][304];
    const int tid = threadIdx.x;
    const int n = blockIdx.x * 256 + tid;
    const long r0 = (long)blockIdx.y * 16;

    for (int i = tid; i < 16 * Ee; i += 256) {
        int r = i / Ee, k = i - r * Ee;
        xs[r][k] = x[(r0 + r) * Ee + k];
    }
    __syncthreads();

    float accx[16], accg[16];
    const float bxv = bx[n], bgv = bg[n];
#pragma unroll
    for (int r = 0; r < 16; r++) { accx[r] = bxv; accg[r] = bgv; }

    for (int k = 0; k < Ee; k += 4) {
        float wx[4], wg[4];
#pragma unroll
        for (int u = 0; u < 4; u++) {
            wx[u] = Wx[(long)(k + u) * Hh + n];
            wg[u] = Wg[(long)(k + u) * Hh + n];
        }
#pragma unroll
        for (int r = 0; r < 16; r++) {
            const float4 xv = *(const float4*)&xs[r][k];
            accx[r] = fmaf(xv.x, wx[0], accx[r]);
            accx[r] = fmaf(xv.y, wx[1], accx[r]);
            accx[r] = fmaf(xv.z, wx[2], accx[r]);
            accx[r] = fmaf(xv.w, wx[3], accx[r]);
            accg[r] = fmaf(xv.x, wg[0], accg[r]);
            accg[r] = fmaf(xv.y, wg[1], accg[r]);
            accg[r] = fmaf(xv.z, wg[2], accg[r]);
            accg[r] = fmaf(xv.w, wg[3], accg[r]);
        }
    }
#pragma unroll
    for (int r = 0; r < 16; r++) {
        const float c = accx[r];
        const float h = sigm(accg[r]) * tanhf(c);
        const long idx = (r0 + r) * Hh + n;
        leaf_c[idx] = c;
        leaf_h[idx] = __float2bfloat16(h);
    }
}

// ---------------------------------------------------------------------------
// Phase 2: schedule. node_l/node_r now encode (child_level << 9) | child_src
// so tree_kernel can classify children hot (level == lev-1) vs cold.
// ---------------------------------------------------------------------------
__global__ __launch_bounds__(64) void sched_kernel(
    const int* __restrict__ trans,
    int* __restrict__ node_l, int* __restrict__ node_r,
    int* __restrict__ root_src, int* __restrict__ offs,
    int* __restrict__ items, int* __restrict__ max_lv,
    int* __restrict__ slots)
{
    __shared__ short stck[Bb][Tt];
    __shared__ unsigned char lvl[Bb][NNODE];
    __shared__ unsigned char trans_s[NSTEP][Bb];
    __shared__ int counts[256];
    __shared__ int offs_s[257];
    __shared__ int maxl_s;
    const int b = threadIdx.x;

    if (b == 0) maxl_s = 0;
    slots[b] = 0;  // 64 dwords = 256 byte-slots
    for (int i = b; i < 256; i += Bb) counts[i] = 0;
    for (int i4 = b; i4 < (NSTEP * Bb) / 4; i4 += Bb) {
        const int4 v = ((const int4*)trans)[i4];
        const int f = 4 * i4;
        trans_s[(f + 0) >> 6][(f + 0) & 63] = (unsigned char)v.x;
        trans_s[(f + 1) >> 6][(f + 1) & 63] = (unsigned char)v.y;
        trans_s[(f + 2) >> 6][(f + 2) & 63] = (unsigned char)v.z;
        trans_s[(f + 3) >> 6][(f + 3) & 63] = (unsigned char)v.w;
    }
    __syncthreads();

    int sp = 0, bp = Tt, nid = 0, maxl = 0;
    for (int t = 0; t < NSTEP; t++) {
        if (trans_s[t][b] == 0) {
            bp -= 1;
            stck[b][sp] = (short)bp; sp += 1;
        } else {
            const int rs = stck[b][sp - 1];
            const int ls = stck[b][sp - 2];
            const int l_lv = (ls < Tt) ? 0 : (int)lvl[b][ls - Tt];
            const int r_lv = (rs < Tt) ? 0 : (int)lvl[b][rs - Tt];
            const int le = 1 + (l_lv > r_lv ? l_lv : r_lv);
            lvl[b][nid] = (unsigned char)le;
            node_l[b * NNODE + nid] = (l_lv << 9) | ls;
            node_r[b * NNODE + nid] = (r_lv << 9) | rs;
            if (le > maxl) maxl = le;
            sp -= 2;
            stck[b][sp] = (short)(Tt + nid); sp += 1;
            nid += 1;
        }
    }
    root_src[b] = (int)stck[b][0];
    for (int i = 0; i < nid; i++) atomicAdd(&counts[lvl[b][i]], 1);
    atomicMax(&maxl_s, maxl);
    __syncthreads();
    if (b == 0) {
        int acc = 0;
        for (int l = 0; l < 256; l++) { offs_s[l] = acc; acc += counts[l]; }
        offs_s[256] = acc;
        max_lv[0] = maxl_s;
    }
    __syncthreads();
    for (int i = b; i < 256; i += Bb) counts[i] = offs_s[i];
    __syncthreads();
    for (int i = 0; i < nid; i++) {
        const int pos = atomicAdd(&counts[lvl[b][i]], 1);
        items[pos] = (b << 16) | i;
    }
    for (int i = b; i < 257; i += Bb) offs[i] = offs_s[i];
}

// ---------------------------------------------------------------------------
// Phase 3: level-synchronous tree evaluation (R4 skeleton + R6 cold/hot split).
// Coherence protocol (proven R4): node h/c written with agent-scope relaxed
// (sc1, -> LLC) by wave 0 only; readers use normal cached loads (each node
// line is written once, pre-barrier, and only read post-barrier; dispatch
// acquire invalidates stale L1/L2). Barrier: byte slot/block, poll by wave 0.
// R6: per-item hot flags (child level == lev-1); cold child fragments are
// gathered BEFORE the poll (latency hidden behind the barrier wait); only
// hot fragments load post-barrier. c-pair packed as one u64 load/store.
// ---------------------------------------------------------------------------
__global__ __launch_bounds__(512) void tree_kernel(
    const float* __restrict__ Wr, const float* __restrict__ br,
    const __hip_bfloat16* __restrict__ leaf_h, const float* __restrict__ leaf_c,
    __hip_bfloat16* __restrict__ node_h, float* __restrict__ node_c,
    const int* __restrict__ node_l, const int* __restrict__ node_r,
    const int* __restrict__ root_src, const int* __restrict__ offs,
    const int* __restrict__ items, const int* __restrict__ max_level,
    float* __restrict__ out, int* __restrict__ slots)
{
    __shared__ __align__(16) __bf16 Wt[16][1032];  // W slice [local col][k], pad +8
    __shared__ float brs[16];
    __shared__ float Cs0[64][17];   // kh=0 partial (left child K-half)
    __shared__ float Cs1[64][17];   // kh=1 partial (right child K-half)
    __shared__ const v8bf* hsl[64];
    __shared__ const v8bf* hsr[64];
    __shared__ const u64* csl[64];  // c-pair (cols 2g,2g+1) as u64*
    __shared__ const u64* csr[64];
    __shared__ int outm[64];        // item | flags (27:hotL 28:hotR 29:pad 30:root)

    const int tid = threadIdx.x;
    const int g = blockIdx.x;  // column group: j = 2g, 2g+1

    // Load W_r slice as bf16, transposed. Local col c: gate=c%5, jj=c/5.
    for (int idx = tid; idx < 16 * 1024; idx += 512) {
        const int c = idx >> 10;
        const int k = idx & 1023;
        float v = 0.f;
        if (c < 10) {
            const int col = (c % 5) * Hh + 2 * g + (c / 5);
            v = Wr[(long)k * N5H + col];
        }
        Wt[c][k] = (__bf16)v;
    }
    if (tid < 16) {
        float v = 0.f;
        if (tid < 10) v = br[(tid % 5) * Hh + 2 * g + (tid / 5)];
        brs[tid] = v;
    }

    const int ML = max_level[0];
    const int wave = tid >> 6;
    const int lane = tid & 63;
    const int quad = lane >> 4;
    const int l15 = lane & 15;
    const int mt = wave & 3;   // M-tile (16 rows each)
    const int kh = wave >> 2;  // K half (0: left child, 1: right child)
    const int mrow = mt * 16 + l15;

    const v8bf* leaf_h8 = (const v8bf*)leaf_h;
    const v8bf* node_h8 = (const v8bf*)node_h;
    u32* node_h32 = (u32*)node_h;  // 2 bf16 per u32

    // prep: build pointer/flag tables for one 64-item chunk targeting level plv.
    // Caller masks to wave 0; m = lane.
    auto prep = [&](int base, int M, int plv) {
        const int m = lane;
        const int it = items[base + (m < M ? m : 0)];
        const int b = it >> 16;
        const int nd = it & 0xffff;
        const int lraw = node_l[b * NNODE + nd];
        const int rraw = node_r[b * NNODE + nd];
        const int ls = lraw & 511, llv = lraw >> 9;
        const int rs = rraw & 511, rlv = rraw >> 9;
        if (ls < Tt) {
            hsl[m] = leaf_h8 + ((long)b * Tt + ls) * (Hh / 8);
            csl[m] = (const u64*)(leaf_c + ((long)b * Tt + ls) * Hh + 2 * g);
        } else {
            hsl[m] = node_h8 + ((long)b * NNODE + (ls - Tt)) * (Hh / 8);
            csl[m] = (const u64*)(node_c + ((long)b * NNODE + (ls - Tt)) * Hh + 2 * g);
        }
        if (rs < Tt) {
            hsr[m] = leaf_h8 + ((long)b * Tt + rs) * (Hh / 8);
            csr[m] = (const u64*)(leaf_c + ((long)b * Tt + rs) * Hh + 2 * g);
        } else {
            hsr[m] = node_h8 + ((long)b * NNODE + (rs - Tt)) * (Hh / 8);
            csr[m] = (const u64*)(node_c + ((long)b * NNODE + (rs - Tt)) * Hh + 2 * g);
        }
        int fl = it;
        if (llv > 0 && llv == plv - 1) fl |= (1 << 27);  // hot left
        if (rlv > 0 && rlv == plv - 1) fl |= (1 << 28);  // hot right
        if (Tt + nd == root_src[b]) fl |= (1 << 30);     // root marker
        if (m >= M) fl |= (1 << 29);                     // pad marker
        outm[m] = fl;
    };

    // Epilogue for current chunk (wave 0 only; sc1 stores stay in wave 0).
    auto epilogue = [&](int lev, float clv0, float clv1, float crv0, float crv1) {
        const int m = lane;
        const int info = outm[m];
        if (!(info & (1 << 29))) {
            const int b = (info >> 16) & 63;
            const int nd = info & 0xffff;
            float hv[2], cv[2];
            const float clv[2] = {clv0, clv1};
            const float crv[2] = {crv0, crv1};
#pragma unroll
            for (int jj = 0; jj < 2; jj++) {
                const float iv = Cs0[m][jj * 5 + 0] + Cs1[m][jj * 5 + 0] + brs[jj * 5 + 0];
                const float fl = Cs0[m][jj * 5 + 1] + Cs1[m][jj * 5 + 1] + brs[jj * 5 + 1];
                const float fr = Cs0[m][jj * 5 + 2] + Cs1[m][jj * 5 + 2] + brs[jj * 5 + 2];
                const float gv = Cs0[m][jj * 5 + 3] + Cs1[m][jj * 5 + 3] + brs[jj * 5 + 3];
                const float ov = Cs0[m][jj * 5 + 4] + Cs1[m][jj * 5 + 4] + brs[jj * 5 + 4];
                cv[jj] = sigm(iv) * tanhf(gv) + sigm(fl) * clv[jj] + sigm(fr) * crv[jj];
                hv[jj] = sigm(ov) * tanhf(cv[jj]);
            }
            union { float f[2]; u64 u; } cp;
            cp.f[0] = cv[0]; cp.f[1] = cv[1];
            __hip_atomic_store((u64*)(node_c + ((long)b * NNODE + nd) * Hh + 2 * g), cp.u,
                               __ATOMIC_RELAXED, __HIP_MEMORY_SCOPE_AGENT);
            const __hip_bfloat16 h0 = __float2bfloat16(hv[0]);
            const __hip_bfloat16 h1 = __float2bfloat16(hv[1]);
            const u32 hpack = (u32)(*(const unsigned short*)&h0)
                            | ((u32)(*(const unsigned short*)&h1) << 16);
            __hip_atomic_store(node_h32 + ((long)b * NNODE + nd) * (Hh / 2) + g, hpack,
                               __ATOMIC_RELAXED, __HIP_MEMORY_SCOPE_AGENT);
            if (info & (1 << 30)) {
                out[(long)b * Hh + 2 * g]     = hv[0];
                out[(long)b * Hh + 2 * g + 1] = hv[1];
            }
        }
    };

    // Initial prep for level 1's first chunk.
    __syncthreads();  // Wt/brs ready (prep doesn't touch them but keep order)
    if (wave == 0) {
        const int s1 = offs[1], e1 = offs[2];
        prep(s1, (e1 - s1 < 64) ? (e1 - s1) : 64, 1);
    }
    __syncthreads();

    for (int lev = 1; lev <= ML; lev++) {
        const int s = offs[lev], e = offs[lev + 1];

        // ---- Phase A (pre-barrier): cold-child gather for chunk 0 ----
        const int info_m = outm[mrow];
        const bool hot = (info_m >> (27 + kh)) & 1;
        const v8bf* hp = kh ? hsr[mrow] : hsl[mrow];
        v8bf a[16];
        if (!hot) {
#pragma unroll
            for (int t = 0; t < 16; t++) a[t] = hp[t * 4 + quad];
        }
        float clv0 = 0.f, clv1 = 0.f, crv0 = 0.f, crv1 = 0.f;
        bool hotL = false, hotR = false;
        if (wave == 0) {
            const int ie = outm[lane];
            hotL = (ie >> 27) & 1;
            hotR = (ie >> 28) & 1;
            union { u64 u; float f[2]; } t;
            if (!hotL) { t.u = *csl[lane]; clv0 = t.f[0]; clv1 = t.f[1]; }
            if (!hotR) { t.u = *csr[lane]; crv0 = t.f[0]; crv1 = t.f[1]; }
        }

        // ---- Barrier wait for level lev-1 (wave 0 polls byte slots) ----
        if (lev > 1 && wave == 0) {
            const u32 need = (u32)(lev - 1);
            const u32* sl = (const u32*)slots + lane;
            for (;;) {
                const u32 v = __hip_atomic_load(sl, __ATOMIC_RELAXED, __HIP_MEMORY_SCOPE_AGENT);
                const bool ok = ((v & 0xffu) >= need) & (((v >> 8) & 0xffu) >= need)
                              & (((v >> 16) & 0xffu) >= need) & ((v >> 24) >= need);
                if (__all(ok)) break;
            }
        }
        __syncthreads();

        // ---- Phase B (post-barrier): hot gather + MFMA for chunk 0 ----
        if (hot) {
#pragma unroll
            for (int t = 0; t < 16; t++) a[t] = hp[t * 4 + quad];
        }
        if (wave == 0) {
            union { u64 u; float f[2]; } t;
            if (hotL) { t.u = *csl[lane]; clv0 = t.f[0]; clv1 = t.f[1]; }
            if (hotR) { t.u = *csr[lane]; crv0 = t.f[0]; crv1 = t.f[1]; }
        }
        v4f acc = {0.f, 0.f, 0.f, 0.f};
#pragma unroll
        for (int t = 0; t < 16; t++) {
            const v8bf wv = *(const v8bf*)&Wt[l15][kh * 512 + t * 32 + quad * 8];
            acc = __builtin_amdgcn_mfma_f32_16x16x32_bf16(a[t], wv, acc, 0, 0, 0);
        }
        {
            float (*Cp)[17] = kh ? Cs1 : Cs0;
#pragma unroll
            for (int rg = 0; rg < 4; rg++) Cp[mt * 16 + quad * 4 + rg][l15] = acc[rg];
        }
        __syncthreads();

        if (wave == 0) epilogue(lev, clv0, clv1, crv0, crv1);

        // ---- Rare extra chunks (>64 items/level): simple post-barrier path ----
        for (int base = s + 64; base < e; base += 64) {
            __syncthreads();
            if (wave == 0) prep(base, (e - base < 64) ? (e - base) : 64, lev);
            __syncthreads();
            float xl0 = 0.f, xl1 = 0.f, xr0 = 0.f, xr1 = 0.f;
            if (wave == 0) {
                union { u64 u; float f[2]; } t;
                t.u = *csl[lane]; xl0 = t.f[0]; xl1 = t.f[1];
                t.u = *csr[lane]; xr0 = t.f[0]; xr1 = t.f[1];
            }
            const v8bf* hp2 = kh ? hsr[mrow] : hsl[mrow];
            v4f acc2 = {0.f, 0.f, 0.f, 0.f};
#pragma unroll
            for (int t = 0; t < 16; t++) {
                const v8bf av = hp2[t * 4 + quad];
                const v8bf wv = *(const v8bf*)&Wt[l15][kh * 512 + t * 32 + quad * 8];
                acc2 = __builtin_amdgcn_mfma_f32_16x16x32_bf16(av, wv, acc2, 0, 0, 0);
            }
            {
                float (*Cp)[17] = kh ? Cs1 : Cs0;
#pragma unroll
                for (int rg = 0; rg < 4; rg++) Cp[mt * 16 + quad * 4 + rg][l15] = acc2[rg];
            }
            __syncthreads();
            if (wave == 0) epilogue(lev, xl0, xl1, xr0, xr1);
        }

        // ---- Arrival + next-level prep (wave 0; arrival first) ----
        if (wave == 0) {
            __builtin_amdgcn_s_waitcnt(0);  // drain wave-0 sc1 stores to LLC
            if (lev < ML) {
                if (lane == 0)
                    __hip_atomic_store((u8*)slots + blockIdx.x, (u8)lev,
                                       __ATOMIC_RELAXED, __HIP_MEMORY_SCOPE_AGENT);
                const int ns = offs[lev + 1], ne = offs[lev + 2];
                prep(ns, (ne - ns < 64) ? (ne - ns) : 64, lev + 1);
            }
        }
        __syncthreads();  // prep visible; Cs/outm safe to reuse
    }
}

// ---------------------------------------------------------------------------
extern "C" void kernel_launch(void* const* d_in, const int* in_sizes, int n_in,
                              void* d_out, int out_size, void* d_ws, size_t ws_size,
                              hipStream_t stream)
{
    const float* x   = (const float*)d_in[0];
    const int* trans = (const int*)d_in[1];
    const float* Wx  = (const float*)d_in[2];
    const float* bx  = (const float*)d_in[3];
    const float* Wg  = (const float*)d_in[4];
    const float* bg  = (const float*)d_in[5];
    const float* Wr  = (const float*)d_in[6];
    const float* br  = (const float*)d_in[7];
    float* out = (float*)d_out;

    char* p = (char*)d_ws;
    auto take = [&](size_t bytes) -> char* {
        char* r = p;
        p += (bytes + 255) & ~(size_t)255;
        return r;
    };
    __hip_bfloat16* leaf_h = (__hip_bfloat16*)take((size_t)Bb * Tt * Hh * 2);
    float* leaf_c          = (float*)take((size_t)Bb * Tt * Hh * 4);
    __hip_bfloat16* node_h = (__hip_bfloat16*)take((size_t)Bb * NNODE * Hh * 2);
    float* node_c          = (float*)take((size_t)Bb * NNODE * Hh * 4);
    int* node_l   = (int*)take((size_t)Bb * NNODE * 4);
    int* node_r   = (int*)take((size_t)Bb * NNODE * 4);
    int* root_src = (int*)take(Bb * 4);
    int* offs     = (int*)take(258 * 4);
    int* items    = (int*)take((size_t)Bb * NNODE * 4);
    int* max_lv   = (int*)take(4);
    int* slots    = (int*)take(64 * 4);   // 256 byte-slots

    hipLaunchKernelGGL(leaf_kernel, dim3(Hh / 256, (Bb * Tt) / 16), dim3(256), 0, stream,
                       x, Wx, bx, Wg, bg, leaf_h, leaf_c);
    hipLaunchKernelGGL(sched_kernel, dim3(1), dim3(64), 0, stream,
                       trans, node_l, node_r, root_src, offs, items, max_lv, slots);

    void* args[] = { (void*)&Wr, (void*)&br, (void*)&leaf_h, (void*)&leaf_c,
                     (void*)&node_h, (void*)&node_c, (void*)&node_l, (void*)&node_r,
                     (void*)&root_src, (void*)&offs, (void*)&items, (void*)&max_lv,
                     (void*)&out, (void*)&slots };
    hipLaunchCooperativeKernel((const void*)tree_kernel, dim3(256), dim3(512),
                               args, 0, stream);
}

// Round 7
// 1669.403 us; speedup vs baseline: 2.3899x; 1.4153x over previous
//
#include <hip/hip_runtime.h>
#include <hip/hip_bf16.h>

// Problem constants (match reference setup_inputs)
#define Bb 64
#define Tt 256
#define Ee 300
#define Hh 512
#define NSTEP (2 * Tt - 1)  // 511
#define NNODE (Tt - 1)      // 255
#define N5H (5 * Hh)        // 2560

// Group decomposition: 4 independent groups x 64 blocks; each group owns 16
// batches end-to-end. Block = member 'mem' of group 'grp' owns 8 j-cols.
#define NG 4
#define GB 64
#define GBATCH 16
#define JPB 8
#define NC 40  // JPB * 5 gate-cols per block

typedef __bf16 v8bf __attribute__((ext_vector_type(8)));
typedef float v4f __attribute__((ext_vector_type(4)));
typedef unsigned long long u64;
typedef unsigned int u32;
typedef unsigned char u8;

__device__ __forceinline__ float sigm(float x) { return 1.f / (1.f + __expf(-x)); }

// ---------------------------------------------------------------------------
// Phase 1: leaf buffer projections (unchanged).
// ---------------------------------------------------------------------------
__global__ __launch_bounds__(256) void leaf_kernel(
    const float* __restrict__ x, const float* __restrict__ Wx,
    const float* __restrict__ bx, const float* __restrict__ Wg,
    const float* __restrict__ bg,
    __hip_bfloat16* __restrict__ leaf_h, float* __restrict__ leaf_c)
{
    __shared__ __align__(16) float xs[16][304];
    const int tid = threadIdx.x;
    const int n = blockIdx.x * 256 + tid;
    const long r0 = (long)blockIdx.y * 16;

    for (int i = tid; i < 16 * Ee; i += 256) {
        int r = i / Ee, k = i - r * Ee;
        xs[r][k] = x[(r0 + r) * Ee + k];
    }
    __syncthreads();

    float accx[16], accg[16];
    const float bxv = bx[n], bgv = bg[n];
#pragma unroll
    for (int r = 0; r < 16; r++) { accx[r] = bxv; accg[r] = bgv; }

    for (int k = 0; k < Ee; k += 4) {
        float wx[4], wg[4];
#pragma unroll
        for (int u = 0; u < 4; u++) {
            wx[u] = Wx[(long)(k + u) * Hh + n];
            wg[u] = Wg[(long)(k + u) * Hh + n];
        }
#pragma unroll
        for (int r = 0; r < 16; r++) {
            const float4 xv = *(const float4*)&xs[r][k];
            accx[r] = fmaf(xv.x, wx[0], accx[r]);
            accx[r] = fmaf(xv.y, wx[1], accx[r]);
            accx[r] = fmaf(xv.z, wx[2], accx[r]);
            accx[r] = fmaf(xv.w, wx[3], accx[r]);
            accg[r] = fmaf(xv.x, wg[0], accg[r]);
            accg[r] = fmaf(xv.y, wg[1], accg[r]);
            accg[r] = fmaf(xv.z, wg[2], accg[r]);
            accg[r] = fmaf(xv.w, wg[3], accg[r]);
        }
    }
#pragma unroll
    for (int r = 0; r < 16; r++) {
        const float c = accx[r];
        const float h = sigm(accg[r]) * tanhf(c);
        const long idx = (r0 + r) * Hh + n;
        leaf_c[idx] = c;
        leaf_h[idx] = __float2bfloat16(h);
    }
}

// ---------------------------------------------------------------------------
// Phase 2: schedule. Per-GROUP level buckets: group g = batch>>4 owns its own
// offs[257] + items list. node_l/r encode (child_level << 9) | child_src.
// Zeroes the 4 x 256 B barrier slot regions.
// ---------------------------------------------------------------------------
__global__ __launch_bounds__(64) void sched_kernel(
    const int* __restrict__ trans,
    int* __restrict__ node_l, int* __restrict__ node_r,
    int* __restrict__ root_src, int* __restrict__ offs,   // [NG*257]
    int* __restrict__ items, int* __restrict__ max_lv,    // [NG*GBATCH*NNODE], [NG]
    int* __restrict__ slots)                              // NG*256 bytes
{
    __shared__ short stck[Bb][Tt];
    __shared__ unsigned char lvl[Bb][NNODE];
    __shared__ unsigned char trans_s[NSTEP][Bb];
    __shared__ int counts[NG][256];
    __shared__ int offs_s[NG][257];
    __shared__ int maxl_s[NG];
    const int b = threadIdx.x;

    if (b < NG) maxl_s[b] = 0;
    for (int i = b; i < NG * 64; i += Bb) slots[i] = 0;  // NG*256 bytes
    for (int i = b; i < NG * 256; i += Bb) counts[i >> 8][i & 255] = 0;
    for (int i4 = b; i4 < (NSTEP * Bb) / 4; i4 += Bb) {
        const int4 v = ((const int4*)trans)[i4];
        const int f = 4 * i4;
        trans_s[(f + 0) >> 6][(f + 0) & 63] = (unsigned char)v.x;
        trans_s[(f + 1) >> 6][(f + 1) & 63] = (unsigned char)v.y;
        trans_s[(f + 2) >> 6][(f + 2) & 63] = (unsigned char)v.z;
        trans_s[(f + 3) >> 6][(f + 3) & 63] = (unsigned char)v.w;
    }
    __syncthreads();

    int sp = 0, bp = Tt, nid = 0, maxl = 0;
    for (int t = 0; t < NSTEP; t++) {
        if (trans_s[t][b] == 0) {
            bp -= 1;
            stck[b][sp] = (short)bp; sp += 1;
        } else {
            const int rs = stck[b][sp - 1];
            const int ls = stck[b][sp - 2];
            const int l_lv = (ls < Tt) ? 0 : (int)lvl[b][ls - Tt];
            const int r_lv = (rs < Tt) ? 0 : (int)lvl[b][rs - Tt];
            const int le = 1 + (l_lv > r_lv ? l_lv : r_lv);
            lvl[b][nid] = (unsigned char)le;
            node_l[b * NNODE + nid] = (l_lv << 9) | ls;
            node_r[b * NNODE + nid] = (r_lv << 9) | rs;
            if (le > maxl) maxl = le;
            sp -= 2;
            stck[b][sp] = (short)(Tt + nid); sp += 1;
            nid += 1;
        }
    }
    root_src[b] = (int)stck[b][0];
    const int g = b >> 4;  // group of this batch
    for (int i = 0; i < nid; i++) atomicAdd(&counts[g][lvl[b][i]], 1);
    atomicMax(&maxl_s[g], maxl);
    __syncthreads();
    if (b < NG) {
        int acc = 0;
        for (int l = 0; l < 256; l++) { offs_s[b][l] = acc; acc += counts[b][l]; }
        offs_s[b][256] = acc;
        max_lv[b] = maxl_s[b];
    }
    __syncthreads();
    for (int i = b; i < NG * 256; i += Bb) counts[i >> 8][i & 255] = offs_s[i >> 8][i & 255];
    __syncthreads();
    for (int i = 0; i < nid; i++) {
        const int pos = atomicAdd(&counts[g][lvl[b][i]], 1);
        items[g * (GBATCH * NNODE) + pos] = (b << 16) | i;
    }
    for (int i = b; i < NG * 257; i += Bb) offs[i] = offs_s[i / 257][i % 257];
}

// ---------------------------------------------------------------------------
// Phase 3: 4 independent groups of 64 blocks. Block (grp, mem) holds W_r cols
// for j in [mem*8, mem*8+8) x 5 gates = 40 cols (80 KB LDS, bf16 transposed).
// Per level per group: 16 nodes (M=16), 8-wave K-split (128 each) MFMA +
// LDS reduce. Sync: 64-byte slot line per group, byte epochs, wave-0 poll.
// Coherence protocol unchanged (proven R4-R6): node h/c stores agent-scope
// relaxed (sc1 -> LLC) from wave 0 only; readers use cached loads (each line
// written once pre-barrier, read only post-barrier, never re-read); leaf
// (cold) child data prefetched BEFORE the poll.
// ---------------------------------------------------------------------------
__global__ __launch_bounds__(512) void tree_kernel(
    const float* __restrict__ Wr, const float* __restrict__ br,
    const __hip_bfloat16* __restrict__ leaf_h, const float* __restrict__ leaf_c,
    __hip_bfloat16* __restrict__ node_h, float* __restrict__ node_c,
    const int* __restrict__ node_l, const int* __restrict__ node_r,
    const int* __restrict__ root_src, const int* __restrict__ offs,
    const int* __restrict__ items, const int* __restrict__ max_lv,
    float* __restrict__ out, int* __restrict__ slots)
{
    __shared__ __align__(16) __bf16 Wt[48][1032];  // [local col][k], pad +8
    __shared__ float Cs[8][16][52];                // per-kq MFMA partials
    __shared__ float Cred[16][44];                 // reduced gates + bias
    __shared__ float brs[48];
    __shared__ u64 hPl[16], hPr[16], cPl[16], cPr[16];
    __shared__ int outm[16];  // item | flags (27:hotL 28:hotR 29:pad 30:root)

    const int tid = threadIdx.x;
    const int blk = blockIdx.x;
    const int grp = blk & 3;   // %4: members of a group land on 2 XCDs (locality heuristic)
    const int mem = blk >> 2;  // 0..63
    const int j0 = mem * JPB;

    const int* offsG = offs + grp * 257;
    const int* itemsG = items + grp * (GBATCH * NNODE);
    u8* slotG = (u8*)slots + grp * 256;

    // Load W_r slice bf16 transposed: local col c -> (gate=c%5, jl=c/5).
    for (int idx = tid; idx < 48 * 1024; idx += 512) {
        const int c = idx >> 10;
        const int k = idx & 1023;
        float v = 0.f;
        if (c < NC) v = Wr[(long)k * N5H + (c % 5) * Hh + j0 + c / 5];
        Wt[c][k] = (__bf16)v;
    }
    if (tid < 48) {
        float v = 0.f;
        if (tid < NC) v = br[(tid % 5) * Hh + j0 + tid / 5];
        brs[tid] = v;
    }

    const int ML = max_lv[grp];
    const int wave = tid >> 6;
    const int lane = tid & 63;
    const int quad = lane >> 4;
    const int l15 = lane & 15;
    const int kq = wave;  // K slice [kq*128, kq*128+128); kq<4 left child, else right

    u32* node_h32 = (u32*)node_h;

    // prep one 16-item chunk (wave 0, lanes < 16).
    auto prep = [&](int base, int M, int plv) {
        if (lane < 16) {
            const int m = lane;
            const int it = itemsG[base + (m < M ? m : 0)];
            const int b = it >> 16;
            const int nd = it & 0xffff;
            const int lraw = node_l[b * NNODE + nd];
            const int rraw = node_r[b * NNODE + nd];
            const int ls = lraw & 511, llv = lraw >> 9;
            const int rs = rraw & 511, rlv = rraw >> 9;
            hPl[m] = (ls < Tt) ? (u64)(leaf_h + ((long)b * Tt + ls) * Hh)
                               : (u64)(node_h + ((long)b * NNODE + (ls - Tt)) * Hh);
            cPl[m] = (ls < Tt) ? (u64)(leaf_c + ((long)b * Tt + ls) * Hh)
                               : (u64)(node_c + ((long)b * NNODE + (ls - Tt)) * Hh);
            hPr[m] = (rs < Tt) ? (u64)(leaf_h + ((long)b * Tt + rs) * Hh)
                               : (u64)(node_h + ((long)b * NNODE + (rs - Tt)) * Hh);
            cPr[m] = (rs < Tt) ? (u64)(leaf_c + ((long)b * Tt + rs) * Hh)
                               : (u64)(node_c + ((long)b * NNODE + (rs - Tt)) * Hh);
            int fl = it;
            if (llv > 0 && llv == plv - 1) fl |= (1 << 27);  // hot left
            if (rlv > 0 && rlv == plv - 1) fl |= (1 << 28);  // hot right
            if (Tt + nd == root_src[b]) fl |= (1 << 30);
            if (m >= M) fl |= (1 << 29);
            outm[m] = fl;
        }
    };

    // Epilogue (wave 0): lane l -> node m=l>>2, local j pair jl2=(l&3)*2.
    auto epilogue = [&](float clv0, float clv1, float crv0, float crv1) {
        const int m = lane >> 2;
        const int jl2 = (lane & 3) * 2;
        const int info = outm[m];
        if (!(info & (1 << 29))) {
            const int b = (info >> 16) & 63;
            const int nd = info & 0xffff;
            float cv[2], hv[2];
            const float clv[2] = {clv0, clv1};
            const float crv[2] = {crv0, crv1};
#pragma unroll
            for (int jj = 0; jj < 2; jj++) {
                const int jc = (jl2 + jj) * 5;
                const float iv = Cred[m][jc + 0];
                const float fl = Cred[m][jc + 1];
                const float fr = Cred[m][jc + 2];
                const float gv = Cred[m][jc + 3];
                const float ov = Cred[m][jc + 4];
                cv[jj] = sigm(iv) * tanhf(gv) + sigm(fl) * clv[jj] + sigm(fr) * crv[jj];
                hv[jj] = sigm(ov) * tanhf(cv[jj]);
            }
            union { float f[2]; u64 u; } cp;
            cp.f[0] = cv[0]; cp.f[1] = cv[1];
            __hip_atomic_store((u64*)(node_c + ((long)b * NNODE + nd) * Hh + j0 + jl2), cp.u,
                               __ATOMIC_RELAXED, __HIP_MEMORY_SCOPE_AGENT);
            const __hip_bfloat16 h0 = __float2bfloat16(hv[0]);
            const __hip_bfloat16 h1 = __float2bfloat16(hv[1]);
            const u32 hpack = (u32)(*(const unsigned short*)&h0)
                            | ((u32)(*(const unsigned short*)&h1) << 16);
            __hip_atomic_store(node_h32 + ((long)b * NNODE + nd) * (Hh / 2) + (j0 + jl2) / 2, hpack,
                               __ATOMIC_RELAXED, __HIP_MEMORY_SCOPE_AGENT);
            if (info & (1 << 30)) {
                out[(long)b * Hh + j0 + jl2]     = hv[0];
                out[(long)b * Hh + j0 + jl2 + 1] = hv[1];
            }
        }
    };

    // MFMA for current chunk from registers a[4]; writes Cs[kq].
    auto do_mfma = [&](v8bf a0, v8bf a1, v8bf a2, v8bf a3) {
        v8bf a[4] = {a0, a1, a2, a3};
#pragma unroll
        for (int nt = 0; nt < 3; nt++) {
            v4f acc = {0.f, 0.f, 0.f, 0.f};
#pragma unroll
            for (int t = 0; t < 4; t++) {
                const v8bf wv = *(const v8bf*)&Wt[nt * 16 + l15][kq * 128 + t * 32 + quad * 8];
                acc = __builtin_amdgcn_mfma_f32_16x16x32_bf16(a[t], wv, acc, 0, 0, 0);
            }
#pragma unroll
            for (int rg = 0; rg < 4; rg++)
                Cs[kq][quad * 4 + rg][nt * 16 + l15] = acc[rg];
        }
    };

    // Reduce Cs over kq + bias -> Cred (all 512 threads).
    auto reduce = [&]() {
        for (int t = tid; t < 16 * NC; t += 512) {
            const int m = t / NC, c = t - m * NC;
            float r = brs[c];
#pragma unroll
            for (int w = 0; w < 8; w++) r += Cs[w][m][c];
            Cred[m][c] = r;
        }
    };

    // Initial prep: level 1, chunk 0.
    if (wave == 0 && ML >= 1) {
        const int s1 = offsG[1], e1 = offsG[2];
        prep(s1, (e1 - s1 < 16) ? (e1 - s1) : 16, 1);
    }
    __syncthreads();

    for (int lev = 1; lev <= ML; lev++) {
        const int s = offsG[lev], e = offsG[lev + 1];

        // ---- Phase A (pre-barrier): cold child gather for chunk 0 ----
        const int infoA = outm[l15];
        const bool hot = (infoA >> (27 + (kq >> 2))) & 1;
        const __hip_bfloat16* hp =
            (const __hip_bfloat16*)((kq < 4) ? hPl[l15] : hPr[l15]);
        const int kb = (kq & 3) * 128 + quad * 8;
        v8bf a0, a1, a2, a3;
        if (!hot) {
            a0 = *(const v8bf*)(hp + kb);
            a1 = *(const v8bf*)(hp + kb + 32);
            a2 = *(const v8bf*)(hp + kb + 64);
            a3 = *(const v8bf*)(hp + kb + 96);
        }
        float clv0 = 0.f, clv1 = 0.f, crv0 = 0.f, crv1 = 0.f;
        bool hotL = false, hotR = false;
        if (wave == 0) {
            const int ie = outm[lane >> 2];
            hotL = (ie >> 27) & 1;
            hotR = (ie >> 28) & 1;
            const int jo = j0 + (lane & 3) * 2;
            if (!hotL) {
                union { u64 u; float f[2]; } t;
                t.u = *(const u64*)((const float*)cPl[lane >> 2] + jo);
                clv0 = t.f[0]; clv1 = t.f[1];
            }
            if (!hotR) {
                union { u64 u; float f[2]; } t;
                t.u = *(const u64*)((const float*)cPr[lane >> 2] + jo);
                crv0 = t.f[0]; crv1 = t.f[1];
            }
        }

        // ---- Barrier: wave 0 polls this group's 64-byte slot line ----
        if (lev > 1 && wave == 0) {
            const u32 need = (u32)(lev - 1);
            const u32* sl = (const u32*)slotG + (lane & 15);
            for (;;) {
                const u32 v = __hip_atomic_load(sl, __ATOMIC_RELAXED, __HIP_MEMORY_SCOPE_AGENT);
                const bool ok = ((v & 0xffu) >= need) & (((v >> 8) & 0xffu) >= need)
                              & (((v >> 16) & 0xffu) >= need) & ((v >> 24) >= need);
                if (__all(ok)) break;
            }
        }
        __syncthreads();

        // ---- Phase B (post-barrier): hot gather + MFMA ----
        if (hot) {
            a0 = *(const v8bf*)(hp + kb);
            a1 = *(const v8bf*)(hp + kb + 32);
            a2 = *(const v8bf*)(hp + kb + 64);
            a3 = *(const v8bf*)(hp + kb + 96);
        }
        if (wave == 0) {
            const int jo = j0 + (lane & 3) * 2;
            if (hotL) {
                union { u64 u; float f[2]; } t;
                t.u = *(const u64*)((const float*)cPl[lane >> 2] + jo);
                clv0 = t.f[0]; clv1 = t.f[1];
            }
            if (hotR) {
                union { u64 u; float f[2]; } t;
                t.u = *(const u64*)((const float*)cPr[lane >> 2] + jo);
                crv0 = t.f[0]; crv1 = t.f[1];
            }
        }
        do_mfma(a0, a1, a2, a3);
        __syncthreads();
        reduce();
        __syncthreads();
        if (wave == 0) epilogue(clv0, clv1, crv0, crv1);

        // ---- Rare extra chunks (>16 items/level): generic path ----
        for (int base = s + 16; base < e; base += 16) {
            __syncthreads();
            if (wave == 0) prep(base, (e - base < 16) ? (e - base) : 16, lev);
            __syncthreads();
            const __hip_bfloat16* hp2 =
                (const __hip_bfloat16*)((kq < 4) ? hPl[l15] : hPr[l15]);
            float xl0 = 0.f, xl1 = 0.f, xr0 = 0.f, xr1 = 0.f;
            if (wave == 0) {
                const int jo = j0 + (lane & 3) * 2;
                union { u64 u; float f[2]; } t;
                t.u = *(const u64*)((const float*)cPl[lane >> 2] + jo);
                xl0 = t.f[0]; xl1 = t.f[1];
                t.u = *(const u64*)((const float*)cPr[lane >> 2] + jo);
                xr0 = t.f[0]; xr1 = t.f[1];
            }
            do_mfma(*(const v8bf*)(hp2 + kb), *(const v8bf*)(hp2 + kb + 32),
                    *(const v8bf*)(hp2 + kb + 64), *(const v8bf*)(hp2 + kb + 96));
            __syncthreads();
            reduce();
            __syncthreads();
            if (wave == 0) epilogue(xl0, xl1, xr0, xr1);
        }

        // ---- Arrival + next-level prep (wave 0) ----
        if (wave == 0) {
            __builtin_amdgcn_s_waitcnt(0);  // drain wave-0 sc1 stores to LLC
            if (lev < ML) {
                if (lane == 0)
                    __hip_atomic_store(slotG + mem, (u8)lev,
                                       __ATOMIC_RELAXED, __HIP_MEMORY_SCOPE_AGENT);
                const int ns = offsG[lev + 1], ne = offsG[lev + 2];
                prep(ns, (ne - ns < 16) ? (ne - ns) : 16, lev + 1);
            }
        }
        __syncthreads();
    }
}

// ---------------------------------------------------------------------------
extern "C" void kernel_launch(void* const* d_in, const int* in_sizes, int n_in,
                              void* d_out, int out_size, void* d_ws, size_t ws_size,
                              hipStream_t stream)
{
    const float* x   = (const float*)d_in[0];
    const int* trans = (const int*)d_in[1];
    const float* Wx  = (const float*)d_in[2];
    const float* bx  = (const float*)d_in[3];
    const float* Wg  = (const float*)d_in[4];
    const float* bg  = (const float*)d_in[5];
    const float* Wr  = (const float*)d_in[6];
    const float* br  = (const float*)d_in[7];
    float* out = (float*)d_out;

    char* p = (char*)d_ws;
    auto take = [&](size_t bytes) -> char* {
        char* r = p;
        p += (bytes + 255) & ~(size_t)255;
        return r;
    };
    __hip_bfloat16* leaf_h = (__hip_bfloat16*)take((size_t)Bb * Tt * Hh * 2);
    float* leaf_c          = (float*)take((size_t)Bb * Tt * Hh * 4);
    __hip_bfloat16* node_h = (__hip_bfloat16*)take((size_t)Bb * NNODE * Hh * 2);
    float* node_c          = (float*)take((size_t)Bb * NNODE * Hh * 4);
    int* node_l   = (int*)take((size_t)Bb * NNODE * 4);
    int* node_r   = (int*)take((size_t)Bb * NNODE * 4);
    int* root_src = (int*)take(Bb * 4);
    int* offs     = (int*)take((size_t)NG * 257 * 4);
    int* items    = (int*)take((size_t)NG * GBATCH * NNODE * 4);
    int* max_lv   = (int*)take(NG * 4);
    int* slots    = (int*)take(NG * 256);  // one 64 B slot line per group, padded

    hipLaunchKernelGGL(leaf_kernel, dim3(Hh / 256, (Bb * Tt) / 16), dim3(256), 0, stream,
                       x, Wx, bx, Wg, bg, leaf_h, leaf_c);
    hipLaunchKernelGGL(sched_kernel, dim3(1), dim3(64), 0, stream,
                       trans, node_l, node_r, root_src, offs, items, max_lv, slots);

    void* args[] = { (void*)&Wr, (void*)&br, (void*)&leaf_h, (void*)&leaf_c,
                     (void*)&node_h, (void*)&node_c, (void*)&node_l, (void*)&node_r,
                     (void*)&root_src, (void*)&offs, (void*)&items, (void*)&max_lv,
                     (void*)&out, (void*)&slots };
    hipLaunchCooperativeKernel((const void*)tree_kernel, dim3(256), dim3(512),
                               args, 0, stream);
}